// Round 3
// baseline (474.036 us; speedup 1.0000x reference)
//
#include <hip/hip_runtime.h>
#include <math.h>

#define HH   4096
#define NKV  8
#define GRP  4
#define HD   128
#define FFN  11008
#define NB   16
#define SC   4096
#define SCALE 0.08838834764831845f   // 1/sqrt(128)
#define SCH  512                      // attention chunk

typedef float f4v __attribute__((ext_vector_type(4)));

__device__ __forceinline__ f4v ntload4(const float* p) {
  return __builtin_nontemporal_load((const f4v*)p);
}
__device__ __forceinline__ float dot4(f4v a, f4v b) {
  return a[0] * b[0] + a[1] * b[1] + a[2] * b[2] + a[3] * b[3];
}

// ---------------------------------------------------------------- RMSNorm
__global__ void rmsnorm_k(const float* __restrict__ x, const float* __restrict__ w,
                          float* __restrict__ y) {
  int b = blockIdx.x;
  const float* xb = x + (size_t)b * HH;
  float* yb = y + (size_t)b * HH;
  int t = threadIdx.x;                       // 256 threads
  int lane = t & 63, wave = t >> 6;
  f4v v[4];
  float ss = 0.f;
#pragma unroll
  for (int i = 0; i < 4; ++i) {
    v[i] = *(const f4v*)(xb + 4 * (t + 256 * i));
    ss += dot4(v[i], v[i]);
  }
#pragma unroll
  for (int m = 1; m < 64; m <<= 1) ss += __shfl_xor(ss, m);
  __shared__ float red[4];
  if (lane == 0) red[wave] = ss;
  __syncthreads();
  float tot = red[0] + red[1] + red[2] + red[3];
  float rs = rsqrtf(tot * (1.0f / HH) + 1e-5f);
#pragma unroll
  for (int i = 0; i < 4; ++i) {
    int h = 4 * (t + 256 * i);
    f4v wv = *(const f4v*)(w + h);
    f4v o = v[i] * rs * wv;
    *(f4v*)(yb + h) = o;
  }
}

// ---------------------------------------------------------------- GEMV (barrier-free, LDS-free)
// Each wave owns 4 W-rows; x read per-step from L2 (x is small and L2-resident).
// MODE 0: qkv fused   W0=Wq,W1=Wk,W2=Wv; x0=xn1; y0=q,y1=k_new,y2=v_new
// MODE 1: Wo + res    W0=Wo; x0=attn; res=hidden; y0=h2
// MODE 2: Wg/Wu pair  W0=Wg,W1=Wu; x0=xn2; y0 = gu = silu(g)*u  (wave: g[p],u[p],g[p+1],u[p+1])
// MODE 3: Wd + res    W0=Wd; x0=gu; res=h2; y0=out
template <int MODE>
__global__ __launch_bounds__(128, 2) void gemv_k(
    const float* __restrict__ W0, const float* __restrict__ W1,
    const float* __restrict__ W2, const float* __restrict__ x0,
    const float* __restrict__ res,
    float* __restrict__ y0, float* __restrict__ y1, float* __restrict__ y2,
    int H) {
  int t = threadIdx.x, lane = t & 63, wave = t >> 6;   // 2 waves/block

  const float* wrow[4];
  int obase;
  if (MODE == 2) {
    int pbase = blockIdx.x * 4 + wave * 2;     // pair index into FFN
    obase = pbase;
    wrow[0] = W0 + (size_t)pbase * H;          // g row p
    wrow[1] = W1 + (size_t)pbase * H;          // u row p
    wrow[2] = W0 + (size_t)(pbase + 1) * H;    // g row p+1
    wrow[3] = W1 + (size_t)(pbase + 1) * H;    // u row p+1
  } else {
    obase = blockIdx.x * 8 + wave * 4;
#pragma unroll
    for (int oi = 0; oi < 4; ++oi) {
      int o = obase + oi;
      const float* wp;
      if (MODE == 0) {
        if (o < 4096) wp = W0 + (size_t)o * H;
        else if (o < 5120) wp = W1 + (size_t)(o - 4096) * H;
        else wp = W2 + (size_t)(o - 5120) * H;
      } else {
        wp = W0 + (size_t)o * H;
      }
      wrow[oi] = wp;
    }
  }

  const float* xp[NB];
#pragma unroll
  for (int b = 0; b < NB; ++b) xp[b] = x0 + (size_t)b * H;

  float acc[4][NB];
#pragma unroll
  for (int oi = 0; oi < 4; ++oi)
#pragma unroll
    for (int b = 0; b < NB; ++b) acc[oi][b] = 0.f;

#pragma unroll 2
  for (int h = 4 * lane; h < H; h += 256) {
    f4v w4[4];
#pragma unroll
    for (int oi = 0; oi < 4; ++oi) w4[oi] = ntload4(wrow[oi] + h);
#pragma unroll
    for (int b = 0; b < NB; ++b) {
      f4v xv = *(const f4v*)(xp[b] + h);
#pragma unroll
      for (int oi = 0; oi < 4; ++oi) acc[oi][b] += dot4(w4[oi], xv);
    }
  }

  // per-wave reduce over lanes via LDS transpose + shfl (intra-wave only, no barrier)
  __shared__ float red[2][NB][68];
  float sarr[4];
#pragma unroll
  for (int oi = 0; oi < 4; ++oi) {
    asm volatile("s_waitcnt lgkmcnt(0)" ::: "memory");
#pragma unroll
    for (int b = 0; b < NB; ++b) red[wave][b][lane] = acc[oi][b];
    asm volatile("s_waitcnt lgkmcnt(0)" ::: "memory");
    int rb = lane & 15, rj = lane >> 4;
    const float* rp = &red[wave][rb][rj * 16];
    f4v a0 = *(const f4v*)rp;
    f4v a1 = *(const f4v*)(rp + 4);
    f4v a2 = *(const f4v*)(rp + 8);
    f4v a3 = *(const f4v*)(rp + 12);
    float s = ((a0[0] + a0[1]) + (a0[2] + a0[3])) + ((a1[0] + a1[1]) + (a1[2] + a1[3])) +
              ((a2[0] + a2[1]) + (a2[2] + a2[3])) + ((a3[0] + a3[1]) + (a3[2] + a3[3]));
    s += __shfl_xor(s, 16);
    s += __shfl_xor(s, 32);
    sarr[oi] = s;
  }
  if (lane < 16) {
    int b = lane;
    if (MODE == 2) {
#pragma unroll
      for (int p = 0; p < 2; ++p) {
        float g = sarr[2 * p], u = sarr[2 * p + 1];
        y0[(size_t)b * FFN + (obase + p)] = g / (1.f + __expf(-g)) * u;
      }
    } else {
#pragma unroll
      for (int oi = 0; oi < 4; ++oi) {
        float s = sarr[oi];
        int o = obase + oi;
        if (MODE == 0) {
          if (o < 4096) y0[(size_t)b * 4096 + o] = s;
          else if (o < 5120) y1[(size_t)b * 1024 + (o - 4096)] = s;
          else y2[(size_t)b * 1024 + (o - 5120)] = s;
        } else {
          y0[(size_t)b * 4096 + o] = res[(size_t)b * 4096 + o] + s;
        }
      }
    }
  }
}

// ---------------------------------------------------------------- attention: split-S partials
__global__ __launch_bounds__(256, 4) void attn_part_k(
    const float* __restrict__ q, const float* __restrict__ kc,
    const float* __restrict__ vc, float* __restrict__ pm,
    float* __restrict__ pl, float* __restrict__ pacc) {
  int c = blockIdx.x, kv = blockIdx.y, b = blockIdx.z;
  int t = threadIdx.x, lane = t & 63, wave = t >> 6;
  int ds = lane & 15, ss = lane >> 4;    // 16 lanes/position, 4 positions/wave-step
  __shared__ float sc[GRP][SCH];         // 8 KB scores
  __shared__ float mg[GRP];
  __shared__ float accw[4][GRP][HD];     // 8 KB per-wave PV partials
  __shared__ float lw[4][GRP];

  f4v qv[GRP][2];
  const float* qb = q + (size_t)b * HH + (size_t)kv * GRP * HD;
#pragma unroll
  for (int g = 0; g < GRP; ++g) {
    qv[g][0] = *(const f4v*)(qb + g * HD + 8 * ds);
    qv[g][1] = *(const f4v*)(qb + g * HD + 8 * ds + 4);
  }
  const size_t kvoff = ((size_t)b * NKV + kv) * (size_t)SC * HD;
  const float* kb = kc + kvoff;

  // pass 1: scores
  for (int st = 0; st < SCH / 16; ++st) {
    int sl = st * 16 + wave * 4 + ss;
    const float* kr = kb + (size_t)(c * SCH + sl) * HD + 8 * ds;
    f4v k0 = ntload4(kr);
    f4v k1 = ntload4(kr + 4);
    float d[GRP];
#pragma unroll
    for (int g = 0; g < GRP; ++g)
      d[g] = dot4(qv[g][0], k0) + dot4(qv[g][1], k1);
#pragma unroll
    for (int m = 1; m < 16; m <<= 1)
#pragma unroll
      for (int g = 0; g < GRP; ++g) d[g] += __shfl_xor(d[g], m);
    if (ds < GRP) sc[ds][sl] = d[ds] * SCALE;
  }
  __syncthreads();

  // per-group max over chunk (wave g handles group g)
  {
    int g = wave;
    float m = -1e30f;
    for (int i = lane; i < SCH; i += 64) m = fmaxf(m, sc[g][i]);
#pragma unroll
    for (int mm = 1; mm < 64; mm <<= 1) m = fmaxf(m, __shfl_xor(m, mm));
    if (lane == 0) mg[g] = m;
  }
  __syncthreads();
  float mreg[GRP];
#pragma unroll
  for (int g = 0; g < GRP; ++g) mreg[g] = mg[g];

  // pass 2: exp + PV
  float acc[GRP][8];
  float lacc[GRP];
#pragma unroll
  for (int g = 0; g < GRP; ++g) {
    lacc[g] = 0.f;
#pragma unroll
    for (int j = 0; j < 8; ++j) acc[g][j] = 0.f;
  }
  const float* vb = vc + kvoff;
  for (int st = 0; st < SCH / 16; ++st) {
    int sl = st * 16 + wave * 4 + ss;
    const float* vr = vb + (size_t)(c * SCH + sl) * HD + 8 * ds;
    f4v v0 = ntload4(vr);
    f4v v1 = ntload4(vr + 4);
    float p[GRP];
#pragma unroll
    for (int g = 0; g < GRP; ++g) p[g] = __expf(sc[g][sl] - mreg[g]);
    if (ds == 0) {
#pragma unroll
      for (int g = 0; g < GRP; ++g) lacc[g] += p[g];
    }
#pragma unroll
    for (int g = 0; g < GRP; ++g) {
#pragma unroll
      for (int j = 0; j < 4; ++j) {
        acc[g][j] += p[g] * v0[j];
        acc[g][4 + j] += p[g] * v1[j];
      }
    }
  }
  // reduce over the 4 position-subgroups
#pragma unroll
  for (int m = 16; m < 64; m <<= 1) {
#pragma unroll
    for (int g = 0; g < GRP; ++g) {
#pragma unroll
      for (int j = 0; j < 8; ++j) acc[g][j] += __shfl_xor(acc[g][j], m);
      lacc[g] += __shfl_xor(lacc[g], m);
    }
  }
  if (ss == 0) {
#pragma unroll
    for (int g = 0; g < GRP; ++g) {
#pragma unroll
      for (int j = 0; j < 4; ++j) {
        accw[wave][g][8 * ds + j] = acc[g][j];
        accw[wave][g][8 * ds + 4 + j] = acc[g][4 + j];
      }
    }
    if (ds == 0) {
#pragma unroll
      for (int g = 0; g < GRP; ++g) lw[wave][g] = lacc[g];
    }
  }
  __syncthreads();

  size_t pbase = (((size_t)(b * NKV + kv)) * 8 + c) * GRP;  // 8 chunks
  for (int idx = t; idx < GRP * HD; idx += 256) {
    int g = idx >> 7, dd = idx & 127;
    float o = accw[0][g][dd] + accw[1][g][dd] + accw[2][g][dd] + accw[3][g][dd];
    pacc[(pbase + g) * HD + dd] = o;
  }
  if (t < GRP) {
    pm[pbase + t] = mg[t];
    pl[pbase + t] = lw[0][t] + lw[1][t] + lw[2][t] + lw[3][t];
  }
}

// ---------------------------------------------------------------- attention: reduce + new token
__global__ void attn_red_k(const float* __restrict__ q, const float* __restrict__ knew,
                           const float* __restrict__ vnew, const float* __restrict__ pm,
                           const float* __restrict__ pl, const float* __restrict__ pacc,
                           float* __restrict__ attn) {
  int bi = blockIdx.x;                 // 128 = 16b * 8kv
  int b = bi >> 3, kv = bi & 7;
  int t = threadIdx.x, lane = t & 63, wave = t >> 6;
  __shared__ float sn[GRP];
  {
    int g = wave;                      // 4 waves, one per group
    float2 qv = *(const float2*)(q + (size_t)b * HH + (size_t)(kv * GRP + g) * HD + 2 * lane);
    float2 k2 = *(const float2*)(knew + (size_t)b * (NKV * HD) + kv * HD + 2 * lane);
    float d = qv.x * k2.x + qv.y * k2.y;
#pragma unroll
    for (int m = 1; m < 64; m <<= 1) d += __shfl_xor(d, m);
    if (lane == 0) sn[g] = d * SCALE;
  }
  __syncthreads();
  size_t base = ((size_t)(b * NKV + kv)) * 8;
  for (int idx = t; idx < GRP * HD; idx += 256) {
    int g = idx >> 7, dd = idx & 127;
    float snv = sn[g];
    float M = snv;
    float pmv[8];
#pragma unroll
    for (int cc = 0; cc < 8; ++cc) {
      pmv[cc] = pm[(base + cc) * GRP + g];
      M = fmaxf(M, pmv[cc]);
    }
    float en = __expf(snv - M);
    float L = en;
    float o = en * vnew[(size_t)b * (NKV * HD) + kv * HD + dd];
#pragma unroll
    for (int cc = 0; cc < 8; ++cc) {
      float f = __expf(pmv[cc] - M);
      L += f * pl[(base + cc) * GRP + g];
      o += f * pacc[((base + cc) * GRP + g) * HD + dd];
    }
    attn[(size_t)b * HH + (size_t)(kv * GRP + g) * HD + dd] = o / L;
  }
}

// ---------------------------------------------------------------- launch
extern "C" void kernel_launch(void* const* d_in, const int* in_sizes, int n_in,
                              void* d_out, int out_size, void* d_ws, size_t ws_size,
                              hipStream_t stream) {
  const float* hidden = (const float*)d_in[0];
  const float* kc = (const float*)d_in[1];
  const float* vc = (const float*)d_in[2];
  const float* Wq = (const float*)d_in[3];
  const float* Wk = (const float*)d_in[4];
  const float* Wv = (const float*)d_in[5];
  const float* Wo = (const float*)d_in[6];
  const float* Wg = (const float*)d_in[7];
  const float* Wu = (const float*)d_in[8];
  const float* Wd = (const float*)d_in[9];
  const float* ln1 = (const float*)d_in[10];
  const float* ln2 = (const float*)d_in[11];
  float* out = (float*)d_out;

  float* ws = (float*)d_ws;
  float* xn1 = ws;                 // 65536
  float* qb = xn1 + 65536;         // 65536
  float* kn = qb + 65536;          // 16384
  float* vn = kn + 16384;          // 16384
  float* attn = vn + 16384;        // 65536
  float* h2 = attn + 65536;        // 65536
  float* xn2 = h2 + 65536;         // 65536
  float* gu = xn2 + 65536;         // 176128  (silu(g)*u fused)
  float* pm = gu + 176128;         // 4096
  float* pl = pm + 4096;           // 4096
  float* pacc = pl + 4096;         // 524288

  rmsnorm_k<<<16, 256, 0, stream>>>(hidden, ln1, xn1);
  gemv_k<0><<<768, 128, 0, stream>>>(Wq, Wk, Wv, xn1, nullptr,
                                     qb, kn, vn, 4096);
  attn_part_k<<<dim3(8, 8, 16), 256, 0, stream>>>(qb, kc, vc, pm, pl, pacc);
  attn_red_k<<<128, 256, 0, stream>>>(qb, kn, vn, pm, pl, pacc, attn);
  gemv_k<1><<<512, 128, 0, stream>>>(Wo, nullptr, nullptr, attn, hidden,
                                     h2, nullptr, nullptr, 4096);
  rmsnorm_k<<<16, 256, 0, stream>>>(h2, ln2, xn2);
  gemv_k<2><<<2752, 128, 0, stream>>>(Wg, Wu, nullptr, xn2, nullptr,
                                      gu, nullptr, nullptr, 4096);
  gemv_k<3><<<512, 128, 0, stream>>>(Wd, nullptr, nullptr, gu, h2,
                                     out, nullptr, nullptr, 11008);
}

// Round 4
// 286.346 us; speedup vs baseline: 1.6555x; 1.6555x over previous
//
#include <hip/hip_runtime.h>
#include <math.h>

#define HH   4096
#define NKV  8
#define GRP  4
#define HD   128
#define FFN  11008
#define NB   16
#define SC   4096
#define SCALE 0.08838834764831845f   // 1/sqrt(128)
#define SCH  512                      // attention chunk

typedef float f4v __attribute__((ext_vector_type(4)));
typedef float f32x4 __attribute__((ext_vector_type(4)));
typedef short bf16x8 __attribute__((ext_vector_type(8)));
typedef unsigned short u16x4 __attribute__((ext_vector_type(4)));

__device__ __forceinline__ f4v ntload4(const float* p) {
  return __builtin_nontemporal_load((const f4v*)p);
}
__device__ __forceinline__ float dot4(f4v a, f4v b) {
  return a[0] * b[0] + a[1] * b[1] + a[2] * b[2] + a[3] * b[3];
}
// fp32 -> bf16 bits, round-to-nearest-even
__device__ __forceinline__ unsigned short f2bf(float f) {
  unsigned int u = __builtin_bit_cast(unsigned int, f);
  u += 0x7fffu + ((u >> 16) & 1u);
  return (unsigned short)(u >> 16);
}

// ---------------------------------------------------------------- RMSNorm 1 (fp32 in, bf16 out)
__global__ void rmsnorm_bf_k(const float* __restrict__ x, const float* __restrict__ w,
                             unsigned short* __restrict__ y) {
  int b = blockIdx.x;
  const float* xb = x + (size_t)b * HH;
  unsigned short* yb = y + (size_t)b * HH;
  int t = threadIdx.x, lane = t & 63, wave = t >> 6;
  f4v v[4];
  float ss = 0.f;
#pragma unroll
  for (int i = 0; i < 4; ++i) {
    v[i] = *(const f4v*)(xb + 4 * (t + 256 * i));
    ss += dot4(v[i], v[i]);
  }
#pragma unroll
  for (int m = 1; m < 64; m <<= 1) ss += __shfl_xor(ss, m);
  __shared__ float red[4];
  if (lane == 0) red[wave] = ss;
  __syncthreads();
  float tot = red[0] + red[1] + red[2] + red[3];
  float rs = rsqrtf(tot * (1.0f / HH) + 1e-5f);
#pragma unroll
  for (int i = 0; i < 4; ++i) {
    int h = 4 * (t + 256 * i);
    f4v wv = *(const f4v*)(w + h);
    f4v o = v[i] * rs * wv;
    u16x4 p;
#pragma unroll
    for (int j = 0; j < 4; ++j) p[j] = f2bf(o[j]);
    *(u16x4*)(yb + h) = p;
  }
}

// ---------------------------------------------------------------- MFMA GEMV (K-split partials)
// D[16 batches][16 rows] per wave via mfma_f32_16x16x32_bf16.
// A: x bf16 [16][H]; B: W fp32 rows converted in-register. Partials: part[kc][b][O].
template <int MODE>
__global__ __launch_bounds__(256, 4) void gemv_mfma_k(
    const float* __restrict__ W0, const float* __restrict__ W1,
    const float* __restrict__ W2, const unsigned short* __restrict__ xbf,
    float* __restrict__ part, int O, int H, int CH) {
  int t = threadIdx.x, lane = t & 63, wave = t >> 6;
  int rb = blockIdx.x, kc = blockIdx.y;
  int obase = rb * 64 + wave * 16;
  int orow = obase + (lane & 15);

  const float* Wp;
  if (MODE == 0) {
    if (orow < 4096) Wp = W0 + (size_t)orow * H;
    else if (orow < 5120) Wp = W1 + (size_t)(orow - 4096) * H;
    else Wp = W2 + (size_t)(orow - 5120) * H;
  } else if (MODE == 2) {
    Wp = (orow < FFN) ? W0 + (size_t)orow * H : W1 + (size_t)(orow - FFN) * H;
  } else {
    Wp = W0 + (size_t)orow * H;
  }

  int k0 = kc * CH + (lane >> 4) * 8;
  const float* wp = Wp + k0;
  const unsigned short* ap = xbf + (size_t)(lane & 15) * H + k0;

  f32x4 acc = {0.f, 0.f, 0.f, 0.f};
  int steps = CH / 32;
#pragma unroll 2
  for (int s = 0; s < steps; ++s) {
    f4v w0 = ntload4(wp);
    f4v w1 = ntload4(wp + 4);
    bf16x8 a = *(const bf16x8*)ap;
    bf16x8 bb;
#pragma unroll
    for (int j = 0; j < 4; ++j) {
      bb[j] = (short)f2bf(w0[j]);
      bb[4 + j] = (short)f2bf(w1[j]);
    }
    acc = __builtin_amdgcn_mfma_f32_16x16x32_bf16(a, bb, acc, 0, 0, 0);
    wp += 32;
    ap += 32;
  }
  // store partial D: batch=(lane>>4)*4+r, col=orow
  float* pb = part + ((size_t)kc * NB + (size_t)((lane >> 4) * 4)) * O + orow;
#pragma unroll
  for (int r = 0; r < 4; ++r) pb[(size_t)r * O] = acc[r];
}

// ---------------------------------------------------------------- reduces
__global__ void red_qkv_k(const float* __restrict__ pq, float* __restrict__ qb,
                          float* __restrict__ kn, float* __restrict__ vn) {
  int idx = blockIdx.x * 256 + threadIdx.x;    // 96*256 threads
  int oi = idx % 1536, b = idx / 1536;
  int o = oi * 4;
  f4v s = {0.f, 0.f, 0.f, 0.f};
#pragma unroll
  for (int ks = 0; ks < 4; ++ks)
    s += *(const f4v*)(pq + ((size_t)(ks * NB + b)) * 6144 + o);
  if (o < 4096) *(f4v*)(qb + (size_t)b * 4096 + o) = s;
  else if (o < 5120) *(f4v*)(kn + (size_t)b * 1024 + (o - 4096)) = s;
  else *(f4v*)(vn + (size_t)b * 1024 + (o - 5120)) = s;
}

// rmsnorm2 fused with Wo-partial reduce + residual: h2 = hidden + sum(p1); xn2 = bf16(rms(h2)*w)
__global__ void rmsnorm2_k(const float* __restrict__ hid, const float* __restrict__ p1,
                           const float* __restrict__ w, float* __restrict__ h2,
                           unsigned short* __restrict__ xn2) {
  int b = blockIdx.x;
  int t = threadIdx.x, lane = t & 63, wave = t >> 6;
  f4v v[4];
  float ss = 0.f;
#pragma unroll
  for (int i = 0; i < 4; ++i) {
    int h = 4 * (t + 256 * i);
    f4v s = *(const f4v*)(hid + (size_t)b * HH + h);
#pragma unroll
    for (int ks = 0; ks < 8; ++ks)
      s += *(const f4v*)(p1 + ((size_t)(ks * NB + b)) * HH + h);
    v[i] = s;
    ss += dot4(s, s);
  }
#pragma unroll
  for (int m = 1; m < 64; m <<= 1) ss += __shfl_xor(ss, m);
  __shared__ float red[4];
  if (lane == 0) red[wave] = ss;
  __syncthreads();
  float tot = red[0] + red[1] + red[2] + red[3];
  float rs = rsqrtf(tot * (1.0f / HH) + 1e-5f);
#pragma unroll
  for (int i = 0; i < 4; ++i) {
    int h = 4 * (t + 256 * i);
    *(f4v*)(h2 + (size_t)b * HH + h) = v[i];
    f4v wv = *(const f4v*)(w + h);
    f4v o = v[i] * rs * wv;
    u16x4 p;
#pragma unroll
    for (int j = 0; j < 4; ++j) p[j] = f2bf(o[j]);
    *(u16x4*)(xn2 + (size_t)b * HH + h) = p;
  }
}

__global__ void red_gu_k(const float* __restrict__ p2, unsigned short* __restrict__ gu) {
  int idx = blockIdx.x * 256 + threadIdx.x;    // 172*256 threads
  int pi = idx % 2752, b = idx / 2752;
  int p = pi * 4;
  const float* g0 = p2 + (size_t)b * 22016 + p;
  f4v g = *(const f4v*)g0 + *(const f4v*)(g0 + (size_t)NB * 22016);
  f4v u = *(const f4v*)(g0 + FFN) + *(const f4v*)(g0 + FFN + (size_t)NB * 22016);
  u16x4 pk;
#pragma unroll
  for (int j = 0; j < 4; ++j) {
    float gg = g[j];
    pk[j] = f2bf(gg / (1.f + __expf(-gg)) * u[j]);
  }
  *(u16x4*)(gu + (size_t)b * FFN + p) = pk;
}

__global__ void red_out_k(const float* __restrict__ h2, const float* __restrict__ p3,
                          float* __restrict__ out) {
  int idx = blockIdx.x * 256 + threadIdx.x;    // 64*256 threads
  int o = (idx & 1023) * 4, b = idx >> 10;
  f4v s = *(const f4v*)(h2 + (size_t)b * HH + o);
#pragma unroll
  for (int ks = 0; ks < 8; ++ks)
    s += *(const f4v*)(p3 + ((size_t)(ks * NB + b)) * HH + o);
  *(f4v*)(out + (size_t)b * HH + o) = s;
}

// ---------------------------------------------------------------- attention: split-S partials
__global__ __launch_bounds__(256, 4) void attn_part_k(
    const float* __restrict__ q, const float* __restrict__ kc,
    const float* __restrict__ vc, float* __restrict__ pm,
    float* __restrict__ pl, float* __restrict__ pacc) {
  int c = blockIdx.x, kv = blockIdx.y, b = blockIdx.z;
  int t = threadIdx.x, lane = t & 63, wave = t >> 6;
  int ds = lane & 15, ss = lane >> 4;
  __shared__ float sc[GRP][SCH];
  __shared__ float mg[GRP];
  __shared__ float accw[4][GRP][HD];
  __shared__ float lw[4][GRP];

  f4v qv[GRP][2];
  const float* qb = q + (size_t)b * HH + (size_t)kv * GRP * HD;
#pragma unroll
  for (int g = 0; g < GRP; ++g) {
    qv[g][0] = *(const f4v*)(qb + g * HD + 8 * ds);
    qv[g][1] = *(const f4v*)(qb + g * HD + 8 * ds + 4);
  }
  const size_t kvoff = ((size_t)b * NKV + kv) * (size_t)SC * HD;
  const float* kb = kc + kvoff;

  for (int st = 0; st < SCH / 16; ++st) {
    int sl = st * 16 + wave * 4 + ss;
    const float* kr = kb + (size_t)(c * SCH + sl) * HD + 8 * ds;
    f4v k0 = ntload4(kr);
    f4v k1 = ntload4(kr + 4);
    float d[GRP];
#pragma unroll
    for (int g = 0; g < GRP; ++g)
      d[g] = dot4(qv[g][0], k0) + dot4(qv[g][1], k1);
#pragma unroll
    for (int m = 1; m < 16; m <<= 1)
#pragma unroll
      for (int g = 0; g < GRP; ++g) d[g] += __shfl_xor(d[g], m);
    if (ds < GRP) sc[ds][sl] = d[ds] * SCALE;
  }
  __syncthreads();

  {
    int g = wave;
    float m = -1e30f;
    for (int i = lane; i < SCH; i += 64) m = fmaxf(m, sc[g][i]);
#pragma unroll
    for (int mm = 1; mm < 64; mm <<= 1) m = fmaxf(m, __shfl_xor(m, mm));
    if (lane == 0) mg[g] = m;
  }
  __syncthreads();
  float mreg[GRP];
#pragma unroll
  for (int g = 0; g < GRP; ++g) mreg[g] = mg[g];

  float acc[GRP][8];
  float lacc[GRP];
#pragma unroll
  for (int g = 0; g < GRP; ++g) {
    lacc[g] = 0.f;
#pragma unroll
    for (int j = 0; j < 8; ++j) acc[g][j] = 0.f;
  }
  const float* vb = vc + kvoff;
  for (int st = 0; st < SCH / 16; ++st) {
    int sl = st * 16 + wave * 4 + ss;
    const float* vr = vb + (size_t)(c * SCH + sl) * HD + 8 * ds;
    f4v v0 = ntload4(vr);
    f4v v1 = ntload4(vr + 4);
    float p[GRP];
#pragma unroll
    for (int g = 0; g < GRP; ++g) p[g] = __expf(sc[g][sl] - mreg[g]);
    if (ds == 0) {
#pragma unroll
      for (int g = 0; g < GRP; ++g) lacc[g] += p[g];
    }
#pragma unroll
    for (int g = 0; g < GRP; ++g) {
#pragma unroll
      for (int j = 0; j < 4; ++j) {
        acc[g][j] += p[g] * v0[j];
        acc[g][4 + j] += p[g] * v1[j];
      }
    }
  }
#pragma unroll
  for (int m = 16; m < 64; m <<= 1) {
#pragma unroll
    for (int g = 0; g < GRP; ++g) {
#pragma unroll
      for (int j = 0; j < 8; ++j) acc[g][j] += __shfl_xor(acc[g][j], m);
      lacc[g] += __shfl_xor(lacc[g], m);
    }
  }
  if (ss == 0) {
#pragma unroll
    for (int g = 0; g < GRP; ++g) {
#pragma unroll
      for (int j = 0; j < 4; ++j) {
        accw[wave][g][8 * ds + j] = acc[g][j];
        accw[wave][g][8 * ds + 4 + j] = acc[g][4 + j];
      }
    }
    if (ds == 0) {
#pragma unroll
      for (int g = 0; g < GRP; ++g) lw[wave][g] = lacc[g];
    }
  }
  __syncthreads();

  size_t pbase = (((size_t)(b * NKV + kv)) * 8 + c) * GRP;
  for (int idx = t; idx < GRP * HD; idx += 256) {
    int g = idx >> 7, dd = idx & 127;
    float o = accw[0][g][dd] + accw[1][g][dd] + accw[2][g][dd] + accw[3][g][dd];
    pacc[(pbase + g) * HD + dd] = o;
  }
  if (t < GRP) {
    pm[pbase + t] = mg[t];
    pl[pbase + t] = lw[0][t] + lw[1][t] + lw[2][t] + lw[3][t];
  }
}

// ---------------------------------------------------------------- attention: reduce + new token (bf16 out)
__global__ void attn_red_k(const float* __restrict__ q, const float* __restrict__ knew,
                           const float* __restrict__ vnew, const float* __restrict__ pm,
                           const float* __restrict__ pl, const float* __restrict__ pacc,
                           unsigned short* __restrict__ attnb) {
  int bi = blockIdx.x;
  int b = bi >> 3, kv = bi & 7;
  int t = threadIdx.x, lane = t & 63, wave = t >> 6;
  __shared__ float sn[GRP];
  {
    int g = wave;
    float2 qv = *(const float2*)(q + (size_t)b * HH + (size_t)(kv * GRP + g) * HD + 2 * lane);
    float2 k2 = *(const float2*)(knew + (size_t)b * (NKV * HD) + kv * HD + 2 * lane);
    float d = qv.x * k2.x + qv.y * k2.y;
#pragma unroll
    for (int m = 1; m < 64; m <<= 1) d += __shfl_xor(d, m);
    if (lane == 0) sn[g] = d * SCALE;
  }
  __syncthreads();
  size_t base = ((size_t)(b * NKV + kv)) * 8;
  for (int idx = t; idx < GRP * HD; idx += 256) {
    int g = idx >> 7, dd = idx & 127;
    float snv = sn[g];
    float M = snv;
    float pmv[8];
#pragma unroll
    for (int cc = 0; cc < 8; ++cc) {
      pmv[cc] = pm[(base + cc) * GRP + g];
      M = fmaxf(M, pmv[cc]);
    }
    float en = __expf(snv - M);
    float L = en;
    float o = en * vnew[(size_t)b * (NKV * HD) + kv * HD + dd];
#pragma unroll
    for (int cc = 0; cc < 8; ++cc) {
      float f = __expf(pmv[cc] - M);
      L += f * pl[(base + cc) * GRP + g];
      o += f * pacc[((base + cc) * GRP + g) * HD + dd];
    }
    attnb[(size_t)b * HH + (size_t)(kv * GRP + g) * HD + dd] = f2bf(o / L);
  }
}

// ---------------------------------------------------------------- launch
extern "C" void kernel_launch(void* const* d_in, const int* in_sizes, int n_in,
                              void* d_out, int out_size, void* d_ws, size_t ws_size,
                              hipStream_t stream) {
  const float* hidden = (const float*)d_in[0];
  const float* kc = (const float*)d_in[1];
  const float* vc = (const float*)d_in[2];
  const float* Wq = (const float*)d_in[3];
  const float* Wk = (const float*)d_in[4];
  const float* Wv = (const float*)d_in[5];
  const float* Wo = (const float*)d_in[6];
  const float* Wg = (const float*)d_in[7];
  const float* Wu = (const float*)d_in[8];
  const float* Wd = (const float*)d_in[9];
  const float* ln1 = (const float*)d_in[10];
  const float* ln2 = (const float*)d_in[11];
  float* out = (float*)d_out;

  float* ws = (float*)d_ws;
  float* p = ws;
  unsigned short* xn1bf = (unsigned short*)p;  p += 32768;   // 16x4096 bf16
  float* qb = p;    p += 65536;
  float* kn = p;    p += 16384;
  float* vn = p;    p += 16384;
  unsigned short* attnbf = (unsigned short*)p; p += 32768;   // 16x4096 bf16
  float* h2 = p;    p += 65536;
  unsigned short* xn2bf = (unsigned short*)p;  p += 32768;   // 16x4096 bf16
  unsigned short* gubf = (unsigned short*)p;   p += 88064;   // 16x11008 bf16
  float* pm = p;    p += 4096;
  float* pl = p;    p += 4096;
  float* pacc = p;  p += 524288;
  float* pq = p;    p += 393216;   // 4 x 16 x 6144
  float* p1 = p;    p += 524288;   // 8 x 16 x 4096
  float* p2 = p;    p += 704512;   // 2 x 16 x 22016
  float* p3 = p;    p += 524288;   // 8 x 16 x 4096

  rmsnorm_bf_k<<<16, 256, 0, stream>>>(hidden, ln1, xn1bf);
  gemv_mfma_k<0><<<dim3(96, 4), 256, 0, stream>>>(Wq, Wk, Wv, xn1bf, pq, 6144, 4096, 1024);
  red_qkv_k<<<96, 256, 0, stream>>>(pq, qb, kn, vn);
  attn_part_k<<<dim3(8, 8, 16), 256, 0, stream>>>(qb, kc, vc, pm, pl, pacc);
  attn_red_k<<<128, 256, 0, stream>>>(qb, kn, vn, pm, pl, pacc, attnbf);
  gemv_mfma_k<1><<<dim3(64, 8), 256, 0, stream>>>(Wo, nullptr, nullptr, attnbf, p1, 4096, 4096, 512);
  rmsnorm2_k<<<16, 256, 0, stream>>>(hidden, p1, ln2, h2, xn2bf);
  gemv_mfma_k<2><<<dim3(344, 2), 256, 0, stream>>>(Wg, Wu, nullptr, xn2bf, p2, 22016, 4096, 2048);
  red_gu_k<<<172, 256, 0, stream>>>(p2, gubf);
  gemv_mfma_k<3><<<dim3(64, 8), 256, 0, stream>>>(Wd, nullptr, nullptr, gubf, p3, 4096, 11008, 1376);
  red_out_k<<<64, 256, 0, stream>>>(h2, p3, out);
}